// Round 15
// baseline (88.550 us; speedup 1.0000x reference)
//
#include <hip/hip_runtime.h>
#include <hip/hip_bf16.h>
#include <hip/hip_fp16.h>

typedef _Float16 f16;
typedef _Float16 f16x2 __attribute__((ext_vector_type(2)));
typedef _Float16 f16x4 __attribute__((ext_vector_type(4)));
typedef _Float16 f16x8 __attribute__((ext_vector_type(8)));
typedef float f32x4 __attribute__((ext_vector_type(4)));

// Problem constants
#define NB 2
#define NS 2048
#define NDM 1024
#define NH 16
#define NK 32
#define ND 64
#define NM (NB * NS)  // 4096 rows

__device__ __forceinline__ void gload_lds16(const void* g, void* l) {
  __builtin_amdgcn_global_load_lds(
      (const __attribute__((address_space(1))) unsigned int*)g,
      (__attribute__((address_space(3))) unsigned int*)l, 16, 0, 0);
}

__device__ __forceinline__ float dot8(f16x8 a, f16x8 b, float s) {
#if __has_builtin(__builtin_amdgcn_fdot2)
#pragma unroll
  for (int e = 0; e < 4; ++e) {
    f16x2 a2 = {a[2 * e], a[2 * e + 1]};
    f16x2 b2 = {b[2 * e], b[2 * e + 1]};
    s = __builtin_amdgcn_fdot2(a2, b2, s, false);
  }
#else
#pragma unroll
  for (int e = 0; e < 8; ++e) s += (float)a[e] * (float)b[e];
#endif
  return s;
}

// ---------------- fused fp32 -> fp16 convert (x + all 4 weights) --------------
__global__ void cvt_all(const float* __restrict__ x, const float* __restrict__ Wq,
                        const float* __restrict__ Wk, const float* __restrict__ Wv,
                        const float* __restrict__ Wo, f16* __restrict__ out) {
  const int nx = NM * NDM / 4;
  const int nw = NDM * NDM / 4;
  int i = blockIdx.x * 256 + threadIdx.x;
  const float* src;
  float scale = 1.f;
  int r;
  if (i < nx) {
    src = x; r = i;
  } else {
    const int m = (i - nx) >> 18;
    r = (i - nx) & (nw - 1);
    src = (m == 0) ? Wq : (m == 1) ? Wk : (m == 2) ? Wv : Wo;
    if (m == 0) scale = 0.125f;
  }
  float4 v = reinterpret_cast<const float4*>(src)[r];
  f16x4 o = {(f16)(v.x * scale), (f16)(v.y * scale), (f16)(v.z * scale), (f16)(v.w * scale)};
  reinterpret_cast<f16x4*>(out)[i] = o;
}

// ---------------- GEMM1: 128x64 tile, QKV-split epilogue ----------------------
// Grid 48x32 = 1536 blocks = 6/CU (LDS 24KB). 4 waves 2x2, wave tile 64x32.
__global__ __launch_bounds__(256, 2) void gemm64_qkv(
    const f16* __restrict__ A, const f16* __restrict__ Bm,
    f16* __restrict__ Qo, f16* __restrict__ Kh, f16* __restrict__ Vh,
    int M, int N, int K) {
  __shared__ __align__(16) f16 As[128 * 64];  // 16 KB
  __shared__ __align__(16) f16 Bs[64 * 64];   //  8 KB
  const int t = threadIdx.x;
  const int lane = t & 63;
  const int w = t >> 6;
  const int wr = w >> 1, wc = w & 1;  // 2(M) x 2(N)
  const int l15 = lane & 15, l4 = lane >> 4;
  const long row0 = (long)blockIdx.y * 128;
  const long col0 = (long)blockIdx.x * 64;

  const f16* Ap = A + row0 * K;
  const f16* Bp = Bm + col0 * K;

  f32x4 acc[4][2] = {};

  for (int kt = 0; kt < K; kt += 64) {
#pragma unroll
    for (int i = 0; i < 4; ++i) {
      const int s = i * 256 + t;       // A: 128 rows x 8 chunks
      const int r = s >> 3, c = s & 7;
      gload_lds16(Ap + (long)r * K + kt + ((c ^ (r & 7)) * 8), As + s * 8);
    }
#pragma unroll
    for (int i = 0; i < 2; ++i) {
      const int s = i * 256 + t;       // B: 64 rows x 8 chunks
      const int r = s >> 3, c = s & 7;
      gload_lds16(Bp + (long)r * K + kt + ((c ^ (r & 7)) * 8), Bs + s * 8);
    }
    __syncthreads();
#pragma unroll
    for (int ks = 0; ks < 2; ++ks) {
      const int kch = ks * 4 + l4;
      f16x8 af[4], bf[2];
#pragma unroll
      for (int mf = 0; mf < 4; ++mf) {
        const int rr = wr * 64 + mf * 16 + l15;
        af[mf] = *reinterpret_cast<const f16x8*>(As + rr * 64 + ((kch ^ (rr & 7)) * 8));
      }
#pragma unroll
      for (int nf = 0; nf < 2; ++nf) {
        const int rr = wc * 32 + nf * 16 + l15;
        bf[nf] = *reinterpret_cast<const f16x8*>(Bs + rr * 64 + ((kch ^ (rr & 7)) * 8));
      }
#pragma unroll
      for (int mf = 0; mf < 4; ++mf)
#pragma unroll
        for (int nf = 0; nf < 2; ++nf)
          acc[mf][nf] = __builtin_amdgcn_mfma_f32_16x16x32_f16(af[mf], bf[nf], acc[mf][nf], 0, 0, 0);
    }
    __syncthreads();
  }

  // ---- epilogue: QKV split ----
#pragma unroll
  for (int mf = 0; mf < 4; ++mf)
#pragma unroll
    for (int nf = 0; nf < 2; ++nf) {
      const long col = col0 + wc * 32 + nf * 16 + l15;
#pragma unroll
      for (int r = 0; r < 4; ++r) {
        const long row = row0 + wr * 64 + mf * 16 + l4 * 4 + r;
        const float val = acc[mf][nf][r];
        if (col < 1024) {
          Qo[row * 1024 + col] = (f16)val;
        } else {
          const long n2 = col - 1024;
          const int mat = (int)(n2 >> 10);  // 0=K, 1=V
          const int hh = (int)((n2 & 1023) >> 6);
          const int dd = (int)(n2 & 63);
          const int bb = (int)(row >> 11), ss = (int)(row & 2047);
          f16* dst = mat ? Vh : Kh;
          dst[(((long)bb * 16 + hh) * 2048 + ss) * 64 + dd] = (f16)val;
        }
      }
    }
}

// ---------------- GEMM2: 128x64 tile, f32 out (R9-validated, ~10us) -----------
__global__ __launch_bounds__(256, 2) void gemm128x64_f32(
    const f16* __restrict__ A, const f16* __restrict__ Bm,
    float* __restrict__ Cf32, int M, int N, int K) {
  __shared__ __align__(16) f16 As[128 * 64];  // 16 KB
  __shared__ __align__(16) f16 Bs[64 * 64];   //  8 KB
  const int t = threadIdx.x;
  const int lane = t & 63;
  const int w = t >> 6;
  const int wr = w >> 1, wc = w & 1;  // 2(M) x 2(N)
  const int l15 = lane & 15, l4 = lane >> 4;
  const long row0 = (long)blockIdx.y * 128;
  const long col0 = (long)blockIdx.x * 64;

  const f16* Ap = A + row0 * K;
  const f16* Bp = Bm + col0 * K;

  f32x4 acc[4][2] = {};

  for (int kt = 0; kt < K; kt += 64) {
#pragma unroll
    for (int i = 0; i < 4; ++i) {
      const int s = i * 256 + t;       // A: 128 rows x 8 chunks
      const int r = s >> 3, c = s & 7;
      gload_lds16(Ap + (long)r * K + kt + ((c ^ (r & 7)) * 8), As + s * 8);
    }
#pragma unroll
    for (int i = 0; i < 2; ++i) {
      const int s = i * 256 + t;       // B: 64 rows x 8 chunks
      const int r = s >> 3, c = s & 7;
      gload_lds16(Bp + (long)r * K + kt + ((c ^ (r & 7)) * 8), Bs + s * 8);
    }
    __syncthreads();
#pragma unroll
    for (int ks = 0; ks < 2; ++ks) {
      const int kch = ks * 4 + l4;
      f16x8 af[4], bf[2];
#pragma unroll
      for (int mf = 0; mf < 4; ++mf) {
        const int rr = wr * 64 + mf * 16 + l15;
        af[mf] = *reinterpret_cast<const f16x8*>(As + rr * 64 + ((kch ^ (rr & 7)) * 8));
      }
#pragma unroll
      for (int nf = 0; nf < 2; ++nf) {
        const int rr = wc * 32 + nf * 16 + l15;
        bf[nf] = *reinterpret_cast<const f16x8*>(Bs + rr * 64 + ((kch ^ (rr & 7)) * 8));
      }
#pragma unroll
      for (int mf = 0; mf < 4; ++mf)
#pragma unroll
        for (int nf = 0; nf < 2; ++nf)
          acc[mf][nf] = __builtin_amdgcn_mfma_f32_16x16x32_f16(af[mf], bf[nf], acc[mf][nf], 0, 0, 0);
    }
    __syncthreads();
  }

#pragma unroll
  for (int mf = 0; mf < 4; ++mf)
#pragma unroll
    for (int nf = 0; nf < 2; ++nf) {
      const long col = col0 + wc * 32 + nf * 16 + l15;
#pragma unroll
      for (int r = 0; r < 4; ++r) {
        const long row = row0 + wr * 64 + mf * 16 + l4 * 4 + r;
        Cf32[row * N + col] = acc[mf][nf][r];
      }
    }
}

// ---------------- sparse attention v7: lane-local softmax/PV ------------------
__global__ __launch_bounds__(256) void attn_v7(
    const f16* __restrict__ qm, const f16* __restrict__ Kh,
    const f16* __restrict__ Vh, const int* __restrict__ attn_idx,
    f16* __restrict__ aout) {
  __shared__ f16 qs[32][72];
  __shared__ int ism[32][36];

  const int t = threadIdx.x;
  const int w = t >> 6, lane = t & 63;

  const int bid = blockIdx.x;
  const int combo = 4 * (bid & 7) + ((bid >> 3) & 3);
  const int chunk = bid >> 5;
  const int b = combo >> 4, h = combo & 15;
  const int s0 = chunk * 32;
  const long kvbase = (long)combo * 2048 * 64;

  {
    const int bq = t >> 3, part = t & 7;
    const long row = (long)(b * 2048 + s0 + bq);
    *reinterpret_cast<f16x8*>(&qs[bq][part * 8]) =
        *reinterpret_cast<const f16x8*>(qm + row * 1024 + h * 64 + part * 8);
    const int4 iv = *reinterpret_cast<const int4*>(attn_idx + row * 32 + part * 4);
    *reinterpret_cast<int4*>(&ism[bq][part * 4]) = iv;
  }
  __syncthreads();

  const int qg = lane >> 3, c = lane & 7;
  const int bq = w * 8 + qg;
  const f16x8 qv = *reinterpret_cast<const f16x8*>(&qs[bq][c * 8]);
  const f16* kbase = Kh + kvbase + c * 8;
  const f16* vbase = Vh + kvbase + c * 8;

  float sc[32];
#pragma unroll
  for (int jb = 0; jb < 8; ++jb) {
    const int4 r4 = *reinterpret_cast<const int4*>(&ism[bq][jb * 4]);
    const int rr[4] = {r4.x, r4.y, r4.z, r4.w};
#pragma unroll
    for (int i = 0; i < 4; ++i) {
      const f16x8 kk = *reinterpret_cast<const f16x8*>(kbase + (long)rr[i] * 64);
      float s = dot8(qv, kk, 0.f);
      s += __shfl_xor(s, 1, 64);
      s += __shfl_xor(s, 2, 64);
      s += __shfl_xor(s, 4, 64);
      sc[jb * 4 + i] = s;
    }
  }

  float m = sc[0];
#pragma unroll
  for (int jj = 1; jj < 32; ++jj) m = fmaxf(m, sc[jj]);
  float sum = 0.f;
#pragma unroll
  for (int jj = 0; jj < 32; ++jj) {
    sc[jj] = __expf(sc[jj] - m);
    sum += sc[jj];
  }
  const float inv = __frcp_rn(sum);

  float acc[8] = {};
#pragma unroll
  for (int jb = 0; jb < 8; ++jb) {
    const int4 r4 = *reinterpret_cast<const int4*>(&ism[bq][jb * 4]);
    const int rr[4] = {r4.x, r4.y, r4.z, r4.w};
#pragma unroll
    for (int i = 0; i < 4; ++i) {
      const f16x8 vv = *reinterpret_cast<const f16x8*>(vbase + (long)rr[i] * 64);
      const float p = sc[jb * 4 + i];
#pragma unroll
      for (int e = 0; e < 8; ++e) acc[e] += p * (float)vv[e];
    }
  }
  f16x8 oo;
#pragma unroll
  for (int e = 0; e < 8; ++e) oo[e] = (f16)(acc[e] * inv);
  const long orow = (long)(b * 2048 + s0 + bq);
  *reinterpret_cast<f16x8*>(aout + orow * 1024 + h * 64 + c * 8) = oo;
}

// ---------------- launch ------------------------------------------------------
extern "C" void kernel_launch(void* const* d_in, const int* in_sizes, int n_in,
                              void* d_out, int out_size, void* d_ws, size_t ws_size,
                              hipStream_t stream) {
  const float* x = (const float*)d_in[0];
  const int* aidx = (const int*)d_in[1];
  const float* Wq = (const float*)d_in[3];
  const float* Wk = (const float*)d_in[4];
  const float* Wv = (const float*)d_in[5];
  const float* Wo = (const float*)d_in[6];
  float* out = (float*)d_out;

  f16* xh = (f16*)d_ws;                      // 4096x1024
  f16* wqkv = xh + (long)NM * NDM;           // 3072x1024
  f16* woh = wqkv + (long)3 * NDM * NDM;     // 1024x1024
  f16* qm = woh + (long)NDM * NDM;           // 4096x1024 (q, scaled)
  f16* Khm = qm + (long)NM * NDM;
  f16* Vhm = Khm + (long)NM * NDM;
  f16* aout = Vhm + (long)NM * NDM;

  cvt_all<<<(NM * NDM / 4 + 4 * NDM * NDM / 4) / 256, 256, 0, stream>>>(
      x, Wq, Wk, Wv, Wo, xh);

  dim3 g1(3 * NDM / 64, NM / 128);  // 48 x 32 = 1536 blocks, 6/CU
  gemm64_qkv<<<g1, 256, 0, stream>>>(xh, wqkv, qm, Khm, Vhm, NM, 3 * NDM, NDM);

  attn_v7<<<2048, 256, 0, stream>>>(qm, Khm, Vhm, aidx, aout);

  dim3 g2(NDM / 64, NM / 128);  // 16 x 32 = 512 blocks, 2/CU
  gemm128x64_f32<<<g2, 256, 0, stream>>>(aout, woh, out, NM, NDM, NDM);
}

// Round 16
// 85.357 us; speedup vs baseline: 1.0374x; 1.0374x over previous
//
#include <hip/hip_runtime.h>
#include <hip/hip_bf16.h>
#include <hip/hip_fp16.h>

typedef _Float16 f16;
typedef _Float16 f16x2 __attribute__((ext_vector_type(2)));
typedef _Float16 f16x4 __attribute__((ext_vector_type(4)));
typedef _Float16 f16x8 __attribute__((ext_vector_type(8)));
typedef float f32x4 __attribute__((ext_vector_type(4)));

// Problem constants
#define NB 2
#define NS 2048
#define NDM 1024
#define NH 16
#define NK 32
#define ND 64
#define NM (NB * NS)  // 4096 rows

__device__ __forceinline__ void gload_lds16(const void* g, void* l) {
  __builtin_amdgcn_global_load_lds(
      (const __attribute__((address_space(1))) unsigned int*)g,
      (__attribute__((address_space(3))) unsigned int*)l, 16, 0, 0);
}

__device__ __forceinline__ float dot8(f16x8 a, f16x8 b, float s) {
#if __has_builtin(__builtin_amdgcn_fdot2)
#pragma unroll
  for (int e = 0; e < 4; ++e) {
    f16x2 a2 = {a[2 * e], a[2 * e + 1]};
    f16x2 b2 = {b[2 * e], b[2 * e + 1]};
    s = __builtin_amdgcn_fdot2(a2, b2, s, false);
  }
#else
#pragma unroll
  for (int e = 0; e < 8; ++e) s += (float)a[e] * (float)b[e];
#endif
  return s;
}

// ---------------- fused fp32 -> fp16 convert (x + all 4 weights) --------------
__global__ void cvt_all(const float* __restrict__ x, const float* __restrict__ Wq,
                        const float* __restrict__ Wk, const float* __restrict__ Wv,
                        const float* __restrict__ Wo, f16* __restrict__ out) {
  const int nx = NM * NDM / 4;
  const int nw = NDM * NDM / 4;
  int i = blockIdx.x * 256 + threadIdx.x;
  const float* src;
  float scale = 1.f;
  int r;
  if (i < nx) {
    src = x; r = i;
  } else {
    const int m = (i - nx) >> 18;
    r = (i - nx) & (nw - 1);
    src = (m == 0) ? Wq : (m == 1) ? Wk : (m == 2) ? Wv : Wo;
    if (m == 0) scale = 0.125f;
  }
  float4 v = reinterpret_cast<const float4*>(src)[r];
  f16x4 o = {(f16)(v.x * scale), (f16)(v.y * scale), (f16)(v.z * scale), (f16)(v.w * scale)};
  reinterpret_cast<f16x4*>(out)[i] = o;
}

// ---------------- GEMM1: 128x128 m97-structure, QKV-split (measured 42us) -----
// 3 blocks/CU — the measured optimum of the occupancy sweep (R7..R14).
__global__ __launch_bounds__(256, 2) void gemm128_qkv(
    const f16* __restrict__ A, const f16* __restrict__ Bm,
    f16* __restrict__ Qo, f16* __restrict__ Kh, f16* __restrict__ Vh,
    int M, int N, int K) {
  __shared__ __align__(16) f16 As[128 * 64];
  __shared__ __align__(16) f16 Bs[128 * 64];
  const int t = threadIdx.x;
  const int lane = t & 63;
  const int w = t >> 6;
  const int wr = w >> 1, wc = w & 1;
  const long row0 = (long)blockIdx.y * 128;
  const long col0 = (long)blockIdx.x * 128;

  const f16* Ap = A + row0 * K;
  const f16* Bp = Bm + col0 * K;

  f32x4 acc[4][4] = {};

  for (int kt = 0; kt < K; kt += 64) {
#pragma unroll
    for (int i = 0; i < 4; ++i) {
      const int s = i * 256 + t;       // 128 rows x 8 chunks
      const int r = s >> 3, c = s & 7;
      const int cs = c ^ (r & 7);      // pre-swizzled source
      gload_lds16(Ap + (long)r * K + kt + cs * 8, As + s * 8);
      gload_lds16(Bp + (long)r * K + kt + cs * 8, Bs + s * 8);
    }
    __syncthreads();
#pragma unroll
    for (int ks = 0; ks < 2; ++ks) {
      const int kch = ks * 4 + (lane >> 4);
      f16x8 af[4], bf[4];
#pragma unroll
      for (int mf = 0; mf < 4; ++mf) {
        const int rr = wr * 64 + mf * 16 + (lane & 15);
        af[mf] = *reinterpret_cast<const f16x8*>(As + rr * 64 + ((kch ^ (rr & 7)) * 8));
      }
#pragma unroll
      for (int nf = 0; nf < 4; ++nf) {
        const int rr = wc * 64 + nf * 16 + (lane & 15);
        bf[nf] = *reinterpret_cast<const f16x8*>(Bs + rr * 64 + ((kch ^ (rr & 7)) * 8));
      }
#pragma unroll
      for (int mf = 0; mf < 4; ++mf)
#pragma unroll
        for (int nf = 0; nf < 4; ++nf)
          acc[mf][nf] = __builtin_amdgcn_mfma_f32_16x16x32_f16(af[mf], bf[nf], acc[mf][nf], 0, 0, 0);
    }
    __syncthreads();
  }

#pragma unroll
  for (int mf = 0; mf < 4; ++mf)
#pragma unroll
    for (int nf = 0; nf < 4; ++nf) {
      const long col = col0 + wc * 64 + nf * 16 + (lane & 15);
#pragma unroll
      for (int r = 0; r < 4; ++r) {
        const long row = row0 + wr * 64 + mf * 16 + (lane >> 4) * 4 + r;
        const float val = acc[mf][nf][r];
        if (col < 1024) {
          Qo[row * 1024 + col] = (f16)val;
        } else {
          const long n2 = col - 1024;
          const int mat = (int)(n2 >> 10);  // 0=K, 1=V
          const int hh = (int)((n2 & 1023) >> 6);
          const int dd = (int)(n2 & 63);
          const int bb = (int)(row >> 11), ss = (int)(row & 2047);
          f16* dst = mat ? Vh : Kh;
          dst[(((long)bb * 16 + hh) * 2048 + ss) * 64 + dd] = (f16)val;
        }
      }
    }
}

// ---------------- GEMM2: 128x64 tile, f32 out (measured ~10us at N=1024) ------
__global__ __launch_bounds__(256, 2) void gemm128x64_f32(
    const f16* __restrict__ A, const f16* __restrict__ Bm,
    float* __restrict__ Cf32, int M, int N, int K) {
  __shared__ __align__(16) f16 As[128 * 64];  // 16 KB
  __shared__ __align__(16) f16 Bs[64 * 64];   //  8 KB
  const int t = threadIdx.x;
  const int lane = t & 63;
  const int w = t >> 6;
  const int wr = w >> 1, wc = w & 1;  // 2(M) x 2(N)
  const int l15 = lane & 15, l4 = lane >> 4;
  const long row0 = (long)blockIdx.y * 128;
  const long col0 = (long)blockIdx.x * 64;

  const f16* Ap = A + row0 * K;
  const f16* Bp = Bm + col0 * K;

  f32x4 acc[4][2] = {};

  for (int kt = 0; kt < K; kt += 64) {
#pragma unroll
    for (int i = 0; i < 4; ++i) {
      const int s = i * 256 + t;       // A: 128 rows x 8 chunks
      const int r = s >> 3, c = s & 7;
      gload_lds16(Ap + (long)r * K + kt + ((c ^ (r & 7)) * 8), As + s * 8);
    }
#pragma unroll
    for (int i = 0; i < 2; ++i) {
      const int s = i * 256 + t;       // B: 64 rows x 8 chunks
      const int r = s >> 3, c = s & 7;
      gload_lds16(Bp + (long)r * K + kt + ((c ^ (r & 7)) * 8), Bs + s * 8);
    }
    __syncthreads();
#pragma unroll
    for (int ks = 0; ks < 2; ++ks) {
      const int kch = ks * 4 + l4;
      f16x8 af[4], bf[2];
#pragma unroll
      for (int mf = 0; mf < 4; ++mf) {
        const int rr = wr * 64 + mf * 16 + l15;
        af[mf] = *reinterpret_cast<const f16x8*>(As + rr * 64 + ((kch ^ (rr & 7)) * 8));
      }
#pragma unroll
      for (int nf = 0; nf < 2; ++nf) {
        const int rr = wc * 32 + nf * 16 + l15;
        bf[nf] = *reinterpret_cast<const f16x8*>(Bs + rr * 64 + ((kch ^ (rr & 7)) * 8));
      }
#pragma unroll
      for (int mf = 0; mf < 4; ++mf)
#pragma unroll
        for (int nf = 0; nf < 2; ++nf)
          acc[mf][nf] = __builtin_amdgcn_mfma_f32_16x16x32_f16(af[mf], bf[nf], acc[mf][nf], 0, 0, 0);
    }
    __syncthreads();
  }

#pragma unroll
  for (int mf = 0; mf < 4; ++mf)
#pragma unroll
    for (int nf = 0; nf < 2; ++nf) {
      const long col = col0 + wc * 32 + nf * 16 + l15;
#pragma unroll
      for (int r = 0; r < 4; ++r) {
        const long row = row0 + wr * 64 + mf * 16 + l4 * 4 + r;
        Cf32[row * N + col] = acc[mf][nf][r];
      }
    }
}

// ---------------- sparse attention v7: lane-local softmax/PV ------------------
__global__ __launch_bounds__(256) void attn_v7(
    const f16* __restrict__ qm, const f16* __restrict__ Kh,
    const f16* __restrict__ Vh, const int* __restrict__ attn_idx,
    f16* __restrict__ aout) {
  __shared__ f16 qs[32][72];
  __shared__ int ism[32][36];

  const int t = threadIdx.x;
  const int w = t >> 6, lane = t & 63;

  const int bid = blockIdx.x;
  const int combo = 4 * (bid & 7) + ((bid >> 3) & 3);
  const int chunk = bid >> 5;
  const int b = combo >> 4, h = combo & 15;
  const int s0 = chunk * 32;
  const long kvbase = (long)combo * 2048 * 64;

  {
    const int bq = t >> 3, part = t & 7;
    const long row = (long)(b * 2048 + s0 + bq);
    *reinterpret_cast<f16x8*>(&qs[bq][part * 8]) =
        *reinterpret_cast<const f16x8*>(qm + row * 1024 + h * 64 + part * 8);
    const int4 iv = *reinterpret_cast<const int4*>(attn_idx + row * 32 + part * 4);
    *reinterpret_cast<int4*>(&ism[bq][part * 4]) = iv;
  }
  __syncthreads();

  const int qg = lane >> 3, c = lane & 7;
  const int bq = w * 8 + qg;
  const f16x8 qv = *reinterpret_cast<const f16x8*>(&qs[bq][c * 8]);
  const f16* kbase = Kh + kvbase + c * 8;
  const f16* vbase = Vh + kvbase + c * 8;

  float sc[32];
#pragma unroll
  for (int jb = 0; jb < 8; ++jb) {
    const int4 r4 = *reinterpret_cast<const int4*>(&ism[bq][jb * 4]);
    const int rr[4] = {r4.x, r4.y, r4.z, r4.w};
#pragma unroll
    for (int i = 0; i < 4; ++i) {
      const f16x8 kk = *reinterpret_cast<const f16x8*>(kbase + (long)rr[i] * 64);
      float s = dot8(qv, kk, 0.f);
      s += __shfl_xor(s, 1, 64);
      s += __shfl_xor(s, 2, 64);
      s += __shfl_xor(s, 4, 64);
      sc[jb * 4 + i] = s;
    }
  }

  float m = sc[0];
#pragma unroll
  for (int jj = 1; jj < 32; ++jj) m = fmaxf(m, sc[jj]);
  float sum = 0.f;
#pragma unroll
  for (int jj = 0; jj < 32; ++jj) {
    sc[jj] = __expf(sc[jj] - m);
    sum += sc[jj];
  }
  const float inv = __frcp_rn(sum);

  float acc[8] = {};
#pragma unroll
  for (int jb = 0; jb < 8; ++jb) {
    const int4 r4 = *reinterpret_cast<const int4*>(&ism[bq][jb * 4]);
    const int rr[4] = {r4.x, r4.y, r4.z, r4.w};
#pragma unroll
    for (int i = 0; i < 4; ++i) {
      const f16x8 vv = *reinterpret_cast<const f16x8*>(vbase + (long)rr[i] * 64);
      const float p = sc[jb * 4 + i];
#pragma unroll
      for (int e = 0; e < 8; ++e) acc[e] += p * (float)vv[e];
    }
  }
  f16x8 oo;
#pragma unroll
  for (int e = 0; e < 8; ++e) oo[e] = (f16)(acc[e] * inv);
  const long orow = (long)(b * 2048 + s0 + bq);
  *reinterpret_cast<f16x8*>(aout + orow * 1024 + h * 64 + c * 8) = oo;
}

// ---------------- launch ------------------------------------------------------
extern "C" void kernel_launch(void* const* d_in, const int* in_sizes, int n_in,
                              void* d_out, int out_size, void* d_ws, size_t ws_size,
                              hipStream_t stream) {
  const float* x = (const float*)d_in[0];
  const int* aidx = (const int*)d_in[1];
  const float* Wq = (const float*)d_in[3];
  const float* Wk = (const float*)d_in[4];
  const float* Wv = (const float*)d_in[5];
  const float* Wo = (const float*)d_in[6];
  float* out = (float*)d_out;

  f16* xh = (f16*)d_ws;                      // 4096x1024
  f16* wqkv = xh + (long)NM * NDM;           // 3072x1024
  f16* woh = wqkv + (long)3 * NDM * NDM;     // 1024x1024
  f16* qm = woh + (long)NDM * NDM;           // 4096x1024 (q, scaled)
  f16* Khm = qm + (long)NM * NDM;
  f16* Vhm = Khm + (long)NM * NDM;
  f16* aout = Vhm + (long)NM * NDM;

  cvt_all<<<(NM * NDM / 4 + 4 * NDM * NDM / 4) / 256, 256, 0, stream>>>(
      x, Wq, Wk, Wv, Wo, xh);

  dim3 g1(3 * NDM / 128, NM / 128);  // 24 x 32 = 768 blocks, 3/CU
  gemm128_qkv<<<g1, 256, 0, stream>>>(xh, wqkv, qm, Khm, Vhm, NM, 3 * NDM, NDM);

  attn_v7<<<2048, 256, 0, stream>>>(qm, Khm, Vhm, aidx, aout);

  dim3 g2(NDM / 64, NM / 128);  // 16 x 32 = 512 blocks, 2/CU
  gemm128x64_f32<<<g2, 256, 0, stream>>>(aout, woh, out, NM, NDM, NDM);
}